// Round 1
// baseline (218.566 us; speedup 1.0000x reference)
//
#include <hip/hip_runtime.h>
#include <stdint.h>

#define NROWS 8192
#define MCOLS 8192
#define DDIM  64
#define BT    128   // tile edge (both i and j)

// ---------- monotone float <-> uint key (for atomicMax argmax) ----------
__device__ __forceinline__ unsigned f2key(float f) {
  unsigned u = __float_as_uint(f);
  return (u & 0x80000000u) ? ~u : (u | 0x80000000u);
}
__device__ __forceinline__ float key2f(unsigned k) {
  unsigned u = (k & 0x80000000u) ? (k & 0x7fffffffu) : ~k;
  return __uint_as_float(u);
}

// ---------- zero the accumulators (ws is poisoned 0xAA every call) ----------
__global__ void init_kernel(unsigned long long* __restrict__ rk,
                            unsigned long long* __restrict__ ck,
                            float* __restrict__ rs, float* __restrict__ cs) {
  int i = blockIdx.x * 256 + threadIdx.x;
  if (i < NROWS) { rk[i] = 0ull; rs[i] = 0.0f; }
  if (i < MCOLS) { ck[i] = 0ull; cs[i] = 0.0f; }
}

// ---------- squared norms: one wave (64 lanes) per row ----------
__global__ void norms_kernel(const float* __restrict__ x, const float* __restrict__ y,
                             float* __restrict__ xn, float* __restrict__ yn) {
  int gt   = blockIdx.x * 256 + threadIdx.x;
  int wave = gt >> 6;                 // global wave id = row id
  int lane = threadIdx.x & 63;
  const float* src; float* dst; int row;
  if (wave < NROWS) { src = x; dst = xn; row = wave; }
  else              { src = y; dst = yn; row = wave - NROWS; }
  float v = src[(size_t)row * DDIM + lane];
  float s = v * v;
  #pragma unroll
  for (int off = 32; off > 0; off >>= 1) s += __shfl_down(s, off);
  if (lane == 0) dst[row] = s;
}

// ---------- main pass: 128x128 tile per block, 8x8 micro-tile per thread ----------
__global__ __launch_bounds__(256, 2) void tile_kernel(
    const float* __restrict__ x, const float* __restrict__ y,
    const float* __restrict__ xn, const float* __restrict__ yn,
    unsigned long long* __restrict__ row_key, float* __restrict__ row_sum,
    unsigned long long* __restrict__ col_key, float* __restrict__ col_sum)
{
  // transposed tiles: s[k][i], leading dim 132 (pad -> 2-way max write conflict, free)
  __shared__ __align__(16) float sA[DDIM * 132];
  __shared__ __align__(16) float sB[DDIM * 132];

  const int tid = threadIdx.x;
  const int tx  = tid & 15;       // j group
  const int ty  = tid >> 4;       // i group
  const int i0  = blockIdx.y * BT;
  const int j0  = blockIdx.x * BT;

  // ---- stage x tile (transposed) ----
  #pragma unroll
  for (int it = 0; it < 8; ++it) {
    int flat = tid + it * 256;          // 0..2047
    int row  = flat >> 4;               // 0..127
    int kq   = (flat & 15) << 2;        // 0,4,...,60
    float4 v = *(const float4*)(x + (size_t)(i0 + row) * DDIM + kq);
    sA[(kq + 0) * 132 + row] = v.x;
    sA[(kq + 1) * 132 + row] = v.y;
    sA[(kq + 2) * 132 + row] = v.z;
    sA[(kq + 3) * 132 + row] = v.w;
  }
  // ---- stage y tile (transposed) ----
  #pragma unroll
  for (int it = 0; it < 8; ++it) {
    int flat = tid + it * 256;
    int row  = flat >> 4;
    int kq   = (flat & 15) << 2;
    float4 v = *(const float4*)(y + (size_t)(j0 + row) * DDIM + kq);
    sB[(kq + 0) * 132 + row] = v.x;
    sB[(kq + 1) * 132 + row] = v.y;
    sB[(kq + 2) * 132 + row] = v.z;
    sB[(kq + 3) * 132 + row] = v.w;
  }
  __syncthreads();

  // ---- K-loop: 8x8 accumulators ----
  float acc[8][8];
  #pragma unroll
  for (int r = 0; r < 8; ++r)
    #pragma unroll
    for (int c = 0; c < 8; ++c) acc[r][c] = 0.0f;

  #pragma unroll 4
  for (int k = 0; k < DDIM; ++k) {
    float4 a0 = *(const float4*)(sA + k * 132 + ty * 8);
    float4 a1 = *(const float4*)(sA + k * 132 + ty * 8 + 4);
    float4 b0 = *(const float4*)(sB + k * 132 + tx * 8);
    float4 b1 = *(const float4*)(sB + k * 132 + tx * 8 + 4);
    float a[8] = {a0.x, a0.y, a0.z, a0.w, a1.x, a1.y, a1.z, a1.w};
    float b[8] = {b0.x, b0.y, b0.z, b0.w, b1.x, b1.y, b1.z, b1.w};
    #pragma unroll
    for (int r = 0; r < 8; ++r)
      #pragma unroll
      for (int c = 0; c < 8; ++c)
        acc[r][c] = fmaf(a[r], b[c], acc[r][c]);
  }

  // ---- epilogue: d = 2 - sqrt(max(xn+yn-2*dot,0)); e = exp(d) ----
  float xnr[8], ync[8];
  #pragma unroll
  for (int r = 0; r < 8; ++r) xnr[r] = xn[i0 + ty * 8 + r];
  #pragma unroll
  for (int c = 0; c < 8; ++c) ync[c] = yn[j0 + tx * 8 + c];

  float mr[8], sr[8], mc[8], sc[8];
  int   ir[8], ic[8];
  #pragma unroll
  for (int r = 0; r < 8; ++r) { mr[r] = -3.4e38f; sr[r] = 0.0f; ir[r] = 0; }
  #pragma unroll
  for (int c = 0; c < 8; ++c) { mc[c] = -3.4e38f; sc[c] = 0.0f; ic[c] = 0; }

  #pragma unroll
  for (int r = 0; r < 8; ++r) {
    #pragma unroll
    for (int c = 0; c < 8; ++c) {
      float sq = fmaxf(xnr[r] + ync[c] - 2.0f * acc[r][c], 0.0f);
      float d  = 2.0f - sqrtf(sq);
      float e  = __expf(d);
      sr[r] += e;
      sc[c] += e;
      int jg = j0 + tx * 8 + c;
      int ig = i0 + ty * 8 + r;
      // strict > with ascending c (resp. r) keeps FIRST max on exact ties (jnp.argmax semantics)
      if (d > mr[r]) { mr[r] = d; ir[r] = jg; }
      if (d > mc[c]) { mc[c] = d; ic[c] = ig; }
    }
  }

  // ---- in-block reduce via LDS (reuse tile buffers), stride 129 = conflict-free ----
  __syncthreads();
  float* rowm  = sA;                  // [16][BT] stride 129, indexed [tx][ridx]
  float* rows_ = sA + 16 * 129;
  int*   rowi  = (int*)(sA + 32 * 129);
  float* colm  = sB;                  // [16][BT] stride 129, indexed [ty][cidx]
  float* cols_ = sB + 16 * 129;
  int*   coli  = (int*)(sB + 32 * 129);

  #pragma unroll
  for (int r = 0; r < 8; ++r) {
    int ridx = ty * 8 + r;
    rowm [tx * 129 + ridx] = mr[r];
    rows_[tx * 129 + ridx] = sr[r];
    rowi [tx * 129 + ridx] = ir[r];
  }
  #pragma unroll
  for (int c = 0; c < 8; ++c) {
    int cidx = tx * 8 + c;
    colm [ty * 129 + cidx] = mc[c];
    cols_[ty * 129 + cidx] = sc[c];
    coli [ty * 129 + cidx] = ic[c];
  }
  __syncthreads();

  if (tid < BT) {
    // one thread per tile-row: merge 16 partials (q ascending = j ascending, strict > keeps first)
    int ridx = tid;
    float m = -3.4e38f, s = 0.0f; int idx = 0;
    for (int q = 0; q < 16; ++q) {
      float mv = rowm[q * 129 + ridx];
      s += rows_[q * 129 + ridx];
      if (mv > m) { m = mv; idx = rowi[q * 129 + ridx]; }
    }
    int ig = i0 + ridx;
    unsigned long long k64 =
        ((unsigned long long)f2key(m) << 32) | (unsigned long long)(unsigned)(~(unsigned)idx);
    atomicMax(row_key + ig, k64);
    atomicAdd(row_sum + ig, s);
  } else {
    // one thread per tile-col
    int cidx = tid - BT;
    float m = -3.4e38f, s = 0.0f; int idx = 0;
    for (int q = 0; q < 16; ++q) {
      float mv = colm[q * 129 + cidx];
      s += cols_[q * 129 + cidx];
      if (mv > m) { m = mv; idx = coli[q * 129 + cidx]; }
    }
    int jg = j0 + cidx;
    unsigned long long k64 =
        ((unsigned long long)f2key(m) << 32) | (unsigned long long)(unsigned)(~(unsigned)idx);
    atomicMax(col_key + jg, k64);
    atomicAdd(col_sum + jg, s);
  }
}

// ---------- finalize: unpack keys, mutual test, write all outputs ----------
__global__ void finalize_kernel(const unsigned long long* __restrict__ row_key,
                                const float* __restrict__ row_sum,
                                const unsigned long long* __restrict__ col_key,
                                const float* __restrict__ col_sum,
                                float* __restrict__ out)
{
  int j = blockIdx.x * 256 + threadIdx.x;
  if (j >= MCOLS) return;
  unsigned long long ck = col_key[j];
  int   ci   = (int)(~(unsigned)ck);              // choice_cols[j] (argmax over i)
  float cmax = key2f((unsigned)(ck >> 32));       // = Dmat[ci, j]
  float lp_col = cmax - logf(col_sum[j]);

  unsigned long long rk = row_key[ci];
  int   rj   = (int)(~(unsigned)rk);              // choice_rows[ci]
  float rmax = key2f((unsigned)(rk >> 32));
  float lp_row = rmax - logf(row_sum[ci]);

  int mut = (rj == j);
  out[j]                 = mut ? (lp_row + lp_col) : 0.0f;  // log_probs
  out[MCOLS + 2 * j + 0] = (float)ci;                       // dmatches[j,0]
  out[MCOLS + 2 * j + 1] = (float)j;                        // dmatches[j,1]
  out[3 * MCOLS + j]     = mut ? 1.0f : 0.0f;               // mutual
}

extern "C" void kernel_launch(void* const* d_in, const int* in_sizes, int n_in,
                              void* d_out, int out_size, void* d_ws, size_t ws_size,
                              hipStream_t stream) {
  const float* x = (const float*)d_in[0];   // [8192, 64] fp32
  const float* y = (const float*)d_in[1];   // [8192, 64] fp32
  float* out = (float*)d_out;               // 32768 floats

  char* ws = (char*)d_ws;                   // 256 KB used
  unsigned long long* row_key = (unsigned long long*)(ws);
  unsigned long long* col_key = (unsigned long long*)(ws + 65536);
  float* row_sum = (float*)(ws + 131072);
  float* col_sum = (float*)(ws + 163840);
  float* xn      = (float*)(ws + 196608);
  float* yn      = (float*)(ws + 229376);

  init_kernel<<<32, 256, 0, stream>>>(row_key, col_key, row_sum, col_sum);
  norms_kernel<<<4096, 256, 0, stream>>>(x, y, xn, yn);
  dim3 grid(MCOLS / BT, NROWS / BT);        // 64 x 64 tiles
  tile_kernel<<<grid, 256, 0, stream>>>(x, y, xn, yn, row_key, row_sum, col_key, col_sum);
  finalize_kernel<<<32, 256, 0, stream>>>(row_key, row_sum, col_key, col_sum, out);
}